// Round 5
// baseline (164.291 us; speedup 1.0000x reference)
//
#include <hip/hip_runtime.h>
#include <cstdint>

typedef short bf16x8 __attribute__((ext_vector_type(8)));
typedef float f32x4 __attribute__((ext_vector_type(4)));

__device__ __forceinline__ unsigned short f2bf(float f) {
  unsigned u = __builtin_bit_cast(unsigned, f);
  u += 0x7fffu + ((u >> 16) & 1u);  // RNE
  return (unsigned short)(u >> 16);
}
__device__ __forceinline__ float bflo(unsigned u) {
  return __builtin_bit_cast(float, u << 16);
}
__device__ __forceinline__ float bfhi(unsigned u) {
  return __builtin_bit_cast(float, u & 0xffff0000u);
}
__device__ __forceinline__ float fast_tanh(float x) {
  float e = __builtin_amdgcn_exp2f(x * 2.885390081777927f);
  return 1.0f - 2.0f * __builtin_amdgcn_rcpf(e + 1.0f);
}

#if __has_builtin(__builtin_amdgcn_fdot2_f32_bf16)
typedef __bf16 bf16x2 __attribute__((ext_vector_type(2)));
__device__ __forceinline__ float dot2bf(unsigned a, unsigned b, float c) {
  return __builtin_amdgcn_fdot2_f32_bf16(__builtin_bit_cast(bf16x2, a),
                                         __builtin_bit_cast(bf16x2, b), c,
                                         false);
}
#else
__device__ __forceinline__ float dot2bf(unsigned a, unsigned b, float c) {
  c = fmaf(bflo(a), bflo(b), c);
  c = fmaf(bfhi(a), bfhi(b), c);
  return c;
}
#endif

// ---------------------------------------------------------------------------
// Stage 1: per-(ks,bt,co) partial GEMM, M=64(ipos) N=64(kpos) K=1024/nsplit.
// Register ping-pong prefetch; epilogue transposes C through LDS to pos-linear
// then scatters dwords into CHANNEL-LAST part[ks][bt][pos][ci] (L2-absorbed).
// No bias/tanh here (deferred; partials are linear).
// ---------------------------------------------------------------------------
template <int ITERS>
__global__ __launch_bounds__(256) void k_stage1(const float* __restrict__ x,
                                                const float* __restrict__ w1,
                                                float* __restrict__ part) {
  __shared__ __align__(16) char lds_raw[64 * 65 * 4];      // 16640 B
  unsigned short* As = (unsigned short*)lds_raw;           // 64 rows * 40 hw
  unsigned short* Bs = (unsigned short*)(lds_raw + 5120);  // 64 rows * 40 hw
  float* Cs = (float*)lds_raw;                             // 64 x 65 fp32

  const int tid = threadIdx.x;
  const int ks = blockIdx.x >> 7;
  const int bt = (blockIdx.x >> 3) & 15;
  const int co = blockIdx.x & 7;
  const int w = tid >> 6, lane = tid & 63, lm = lane & 15, q = lane >> 4;
  const int rrow = tid & 63, kgr = tid >> 6;

  f32x4 acc[4];
#pragma unroll
  for (int i = 0; i < 4; ++i) acc[i] = (f32x4){0.f, 0.f, 0.f, 0.f};

  const float* gA = x + (bt << 16) + ((size_t)(ks * ITERS * 32) << 6);
  const float* gB = w1 + (co << 6) + (size_t)(ks * ITERS * 32) * 512;

  float va[2][8], vb[2][8];
#define S1_LOAD(buf, it)                            \
  {                                                 \
    const int kb = (it) * 32 + (kgr << 3);          \
    _Pragma("unroll") for (int j = 0; j < 8; ++j) { \
      va[buf][j] = gA[((kb + j) << 6) | rrow];      \
      vb[buf][j] = gB[(kb + j) * 512 + rrow];       \
    }                                               \
  }
  S1_LOAD(0, 0);
#pragma unroll
  for (int it = 0; it < ITERS; ++it) {
    const int cur = it & 1;
    if (it + 1 < ITERS) S1_LOAD(cur ^ 1, it + 1);
    uint4 pa, pb;
    pa.x = f2bf(va[cur][0]) | ((unsigned)f2bf(va[cur][1]) << 16);
    pa.y = f2bf(va[cur][2]) | ((unsigned)f2bf(va[cur][3]) << 16);
    pa.z = f2bf(va[cur][4]) | ((unsigned)f2bf(va[cur][5]) << 16);
    pa.w = f2bf(va[cur][6]) | ((unsigned)f2bf(va[cur][7]) << 16);
    pb.x = f2bf(vb[cur][0]) | ((unsigned)f2bf(vb[cur][1]) << 16);
    pb.y = f2bf(vb[cur][2]) | ((unsigned)f2bf(vb[cur][3]) << 16);
    pb.z = f2bf(vb[cur][4]) | ((unsigned)f2bf(vb[cur][5]) << 16);
    pb.w = f2bf(vb[cur][6]) | ((unsigned)f2bf(vb[cur][7]) << 16);
    *(uint4*)&As[rrow * 40 + (kgr << 3)] = pa;
    *(uint4*)&Bs[rrow * 40 + (kgr << 3)] = pb;
    __syncthreads();
    bf16x8 a = *(const bf16x8*)&As[((w << 4) + lm) * 40 + (q << 3)];
#pragma unroll
    for (int nf = 0; nf < 4; ++nf) {
      bf16x8 b = *(const bf16x8*)&Bs[((nf << 4) + lm) * 40 + (q << 3)];
      acc[nf] = __builtin_amdgcn_mfma_f32_16x16x32_bf16(a, b, acc[nf], 0, 0, 0);
    }
    __syncthreads();
  }
#undef S1_LOAD
  // ---- epilogue: C -> LDS transpose -> pos-linear scatter (stride 8 dw)
#pragma unroll
  for (int nf = 0; nf < 4; ++nf)
#pragma unroll
    for (int r = 0; r < 4; ++r) {
      int m = (w << 4) + (q << 2) + r;
      int n = (nf << 4) + lm;
      Cs[m * 65 + n] = acc[nf][r];
    }
  __syncthreads();
  float* dst = part + (((size_t)((ks << 4) + bt)) << 15) + co;
#pragma unroll
  for (int j = 0; j < 16; ++j) {
    int pos = (tid << 4) + j;
    int z = pos >> 8, y = (pos >> 4) & 15, xx = pos & 15;
    int m = ((z >> 2) << 4) + ((y >> 2) << 2) + (xx >> 2);
    int n = ((z & 3) << 4) + ((y & 3) << 2) + (xx & 3);
    dst[pos << 3] = Cs[m * 65 + n];
  }
}

// ---------------------------------------------------------------------------
// Fused stage 2+3, 512 threads/block, 1024 blocks (out tile z4 x y16 x x8)
// -> 4 blocks/CU. Staging sums K-split partials (channel-last, coalesced)
// + b1 + tanh into packed bf16 h1p. Fill + conv per cio; conv thread =
// (xh, yq, zq, co) -> 4 x-outputs, packed-bf16 dot2.
// ---------------------------------------------------------------------------
__global__ __launch_bounds__(512, 8) void k_stage23(
    const float* __restrict__ part, const float* __restrict__ w2,
    const float* __restrict__ b2, const float* __restrict__ w3,
    const float* __restrict__ b3, const float* __restrict__ b1,
    float* __restrict__ out, int nsplit) {
  __shared__ __align__(16) unsigned win_d[10 * 34 * 12];  // 16320 B
  __shared__ __align__(16) unsigned h1p[4 * 240];         // bf16 pairs, 3840 B
  __shared__ __align__(16) unsigned w2p[8 * 320];         // bf16 pairs, 10240 B
  __shared__ __align__(16) unsigned w3p[1024];            // [cio][kd][kh][pair][c4]

  const int tid = threadIdx.x;
  const int bid = blockIdx.x;
  const int bt = bid >> 6;
  const int tile = bid & 63;
  const int tz = tile >> 3, ty = (tile >> 2) & 1, tx = tile & 3;
  const int Z0 = tz << 2, Y0 = ty << 4, X0 = tx << 3;
  const int Qz0 = (Z0 << 1) - 1, Qy0 = (Y0 << 1) - 1, Qx0 = (X0 << 1) - 1;
  const int Uz0 = (tz << 1) - 1, Uy0 = (ty << 3) - 1, Ux0 = (tx << 2) - 1;

  // ---- staging: h1 = tanh(sum_s part + b1), coalesced reads, bf16 LDS
  for (int l = tid; l < 1920; l += 512) {
    int ci = l & 7;
    int sp = l >> 3;
    int ux = sp % 6;
    int t1 = sp / 6;
    int uy = t1 % 10;
    int uz = t1 / 10;  // 0..3
    int gz = Uz0 + uz, gy = Uy0 + uy, gx = Ux0 + ux;
    float v = 0.f;
    if ((unsigned)gz < 16u && (unsigned)gy < 16u && (unsigned)gx < 16u) {
      const float* p =
          part + (((size_t)bt << 12) + (gz << 8) + (gy << 4) + gx) * 8 + ci;
      float s = b1[ci];
      for (int sg = 0; sg < nsplit; ++sg) s += p[(size_t)sg << 19];
      v = fast_tanh(s);
    }
    ((unsigned short*)h1p)[uz * 480 + uy * 48 + (ux << 3) + ci] = f2bf(v);
  }
  // w2 packed: dword = [cio][kz*4+ky (stride 20dw)][kx*4 + jpair]
  for (int l = tid; l < 2048; l += 512) {
    int j = l & 3, kx = (l >> 2) & 3, kzy = (l >> 4) & 15, cio = l >> 8;
    int kpos = (kzy << 2) + kx;
    float w0 = w2[(((j << 1) << 3) + cio) * 64 + kpos];
    float w1v = w2[((((j << 1) + 1) << 3) + cio) * 64 + kpos];
    w2p[cio * 320 + kzy * 20 + (kx << 2) + j] =
        (unsigned)f2bf(w0) | ((unsigned)f2bf(w1v) << 16);
  }
  for (int l = tid; l < 1024; l += 512) {
    int c4 = l & 3, pair = (l >> 2) & 1, kh = (l >> 3) & 3, kd = (l >> 5) & 3,
        cio = l >> 7;
    int base = (((c4 << 3) + cio) << 6) + (kd << 4) + (kh << 2) + (pair << 1);
    w3p[l] = (unsigned)f2bf(w3[base]) | ((unsigned)f2bf(w3[base + 1]) << 16);
  }

  float acc[4];  // [i] for this thread's single co
#pragma unroll
  for (int i = 0; i < 4; ++i) acc[i] = 0.f;

  const int xh = tid & 1, yq = (tid >> 1) & 15, zq = (tid >> 5) & 3,
            ch = tid >> 7;  // co 0..3

  for (int cio = 0; cio < 8; ++cio) {
    __syncthreads();  // prev conv done reading win (covers staging too)
    const float b2c = b2[cio];
    // ---- fill window: 680 units = (wz 10) x (wy 34) x (half 2)
    for (int u = tid; u < 680; u += 512) {
      int wz = u / 68;
      int rem = u - wz * 68;
      int wy = rem >> 1;
      int half = rem & 1;
      unsigned* wrow = win_d + (wz * 34 + wy) * 12;
      int qz = Qz0 + wz, qy = Qy0 + wy;
      if ((unsigned)qz < 64u && (unsigned)qy < 64u) {
        int kz = qz & 3, ky = qy & 3;
        int uzp = (qz >> 2) - Uz0, uyp = (qy >> 2) - Uy0;
        const unsigned* w2b = w2p + cio * 320 + ((kz << 2) + ky) * 20;
        uint4 wv[4];
#pragma unroll
        for (int kx = 0; kx < 4; ++kx) wv[kx] = *(const uint4*)(w2b + (kx << 2));
        const unsigned* h1b = h1p + uzp * 240 + uyp * 24;
#define DOT8(hc, kx)                                               \
  dot2bf((hc).w, wv[kx].w,                                         \
         dot2bf((hc).z, wv[kx].z,                                  \
                dot2bf((hc).y, wv[kx].y, dot2bf((hc).x, wv[kx].x, b2c))))
        if (half == 0) {  // wx 0..7: cell0 kx3(guard), cell1 kx0-3, cell2 kx0-2
          uint4 h0 = *(const uint4*)(h1b);
          uint4 h1c = *(const uint4*)(h1b + 4);
          uint4 h2c = *(const uint4*)(h1b + 8);
          float vals[8];
          vals[0] = (Qx0 >= 0) ? fast_tanh(DOT8(h0, 3)) : 0.f;
#pragma unroll
          for (int kx = 0; kx < 4; ++kx) vals[1 + kx] = fast_tanh(DOT8(h1c, kx));
#pragma unroll
          for (int kx = 0; kx < 3; ++kx) vals[5 + kx] = fast_tanh(DOT8(h2c, kx));
          uint4 s0;
          s0.x = f2bf(vals[0]) | ((unsigned)f2bf(vals[1]) << 16);
          s0.y = f2bf(vals[2]) | ((unsigned)f2bf(vals[3]) << 16);
          s0.z = f2bf(vals[4]) | ((unsigned)f2bf(vals[5]) << 16);
          s0.w = f2bf(vals[6]) | ((unsigned)f2bf(vals[7]) << 16);
          *(uint4*)wrow = s0;
        } else {  // wx 8..17: cell2 kx3, cell3 kx0-3, cell4 kx0-3, cell5 kx0(guard)
          uint4 h2c = *(const uint4*)(h1b + 8);
          uint4 h3 = *(const uint4*)(h1b + 12);
          uint4 h4 = *(const uint4*)(h1b + 16);
          uint4 h5 = *(const uint4*)(h1b + 20);
          float vals[10];
          vals[0] = fast_tanh(DOT8(h2c, 3));
#pragma unroll
          for (int kx = 0; kx < 4; ++kx) vals[1 + kx] = fast_tanh(DOT8(h3, kx));
#pragma unroll
          for (int kx = 0; kx < 4; ++kx) vals[5 + kx] = fast_tanh(DOT8(h4, kx));
          vals[9] = (Qx0 + 17 < 64) ? fast_tanh(DOT8(h5, 0)) : 0.f;
          uint4 s1;
          s1.x = f2bf(vals[0]) | ((unsigned)f2bf(vals[1]) << 16);
          s1.y = f2bf(vals[2]) | ((unsigned)f2bf(vals[3]) << 16);
          s1.z = f2bf(vals[4]) | ((unsigned)f2bf(vals[5]) << 16);
          s1.w = f2bf(vals[6]) | ((unsigned)f2bf(vals[7]) << 16);
          *(uint4*)(wrow + 4) = s1;
          wrow[8] = f2bf(vals[8]) | ((unsigned)f2bf(vals[9]) << 16);
        }
#undef DOT8
      } else {
        uint4 zz;
        zz.x = zz.y = zz.z = zz.w = 0u;
        if (half == 0) {
          *(uint4*)wrow = zz;
        } else {
          *(uint4*)(wrow + 4) = zz;
          wrow[8] = 0u;
        }
      }
    }
    __syncthreads();
    // ---- conv3 accumulation for this cio (packed bf16 dot2), 1 co/thread
#pragma unroll
    for (int kd = 0; kd < 4; ++kd) {
      int wz = (zq << 1) + kd;
#pragma unroll
      for (int kh = 0; kh < 4; ++kh) {
        int wy = (yq << 1) + kh;
        const unsigned* rowp = win_d + (wz * 34 + wy) * 12 + (xh << 2);
        uint4 rv = *(const uint4*)rowp;
        unsigned r4 = rowp[4];
        unsigned r[5] = {rv.x, rv.y, rv.z, rv.w, r4};
        const unsigned* wp = w3p + (((cio << 4) + (kd << 2) + kh) << 3);
        unsigned wA = wp[ch];
        unsigned wB = wp[4 + ch];
#pragma unroll
        for (int i = 0; i < 4; ++i) {
          float a0 = dot2bf(r[i], wA, acc[i]);
          acc[i] = dot2bf(r[i + 1], wB, a0);
        }
      }
    }
  }
  // ---- epilogue: + b3, store to (B, C, 32,32,32, T) with t innermost
  const int b = bt >> 3, t8 = bt & 7;
  const int z = Z0 + zq;
  const int y = Y0 + yq;
  const float bias = b3[ch];
#pragma unroll
  for (int i = 0; i < 4; ++i) {
    int xx = X0 + (xh << 2) + i;
    out[(((((b << 2) + ch) * 32 + z) * 32 + y) * 32 + xx) << 3 | t8] =
        acc[i] + bias;
  }
}

extern "C" void kernel_launch(void* const* d_in, const int* in_sizes, int n_in,
                              void* d_out, int out_size, void* d_ws,
                              size_t ws_size, hipStream_t stream) {
  (void)in_sizes; (void)n_in; (void)out_size;
  const float* x = (const float*)d_in[0];
  const float* w1 = (const float*)d_in[1];
  const float* b1 = (const float*)d_in[2];
  const float* w2 = (const float*)d_in[3];
  const float* b2 = (const float*)d_in[4];
  const float* w3 = (const float*)d_in[5];
  const float* b3 = (const float*)d_in[6];
  float* out = (float*)d_out;
  float* part = (float*)d_ws;

  const size_t plane_bytes = (size_t)16 * 8 * 4096 * 4;  // 2 MB per split
  int nsplit = (ws_size >= 2 * plane_bytes) ? 2 : 1;
  if (nsplit == 2)
    k_stage1<16><<<dim3(256), dim3(256), 0, stream>>>(x, w1, part);
  else
    k_stage1<32><<<dim3(128), dim3(256), 0, stream>>>(x, w1, part);
  k_stage23<<<dim3(1024), dim3(512), 0, stream>>>(part, w2, b2, w3, b3, b1, out,
                                                  nsplit);
}

// Round 6
// 156.937 us; speedup vs baseline: 1.0469x; 1.0469x over previous
//
#include <hip/hip_runtime.h>
#include <cstdint>

typedef short bf16x8 __attribute__((ext_vector_type(8)));
typedef float f32x4 __attribute__((ext_vector_type(4)));

__device__ __forceinline__ unsigned short f2bf(float f) {
  unsigned u = __builtin_bit_cast(unsigned, f);
  u += 0x7fffu + ((u >> 16) & 1u);  // RNE
  return (unsigned short)(u >> 16);
}
__device__ __forceinline__ float bflo(unsigned u) {
  return __builtin_bit_cast(float, u << 16);
}
__device__ __forceinline__ float bfhi(unsigned u) {
  return __builtin_bit_cast(float, u & 0xffff0000u);
}
__device__ __forceinline__ float fast_tanh(float x) {
  float e = __builtin_amdgcn_exp2f(x * 2.885390081777927f);
  return 1.0f - 2.0f * __builtin_amdgcn_rcpf(e + 1.0f);
}

#if __has_builtin(__builtin_amdgcn_fdot2_f32_bf16)
typedef __bf16 bf16x2 __attribute__((ext_vector_type(2)));
__device__ __forceinline__ float dot2bf(unsigned a, unsigned b, float c) {
  return __builtin_amdgcn_fdot2_f32_bf16(__builtin_bit_cast(bf16x2, a),
                                         __builtin_bit_cast(bf16x2, b), c,
                                         false);
}
#else
__device__ __forceinline__ float dot2bf(unsigned a, unsigned b, float c) {
  c = fmaf(bflo(a), bflo(b), c);
  c = fmaf(bfhi(a), bfhi(b), c);
  return c;
}
#endif

// ---------------------------------------------------------------------------
// Stage 1: per-(ks,bt,co) partial GEMM, M=64(ipos) N=64(kpos) K=1024/nsplit.
// Register ping-pong prefetch; epilogue transposes C through LDS to pos-linear
// then scatters dwords into CHANNEL-LAST part[ks][bt][pos][ci] (L2-absorbed).
// Block 0 additionally packs w3 into wtab (global) for stage23's scalar loads.
// ---------------------------------------------------------------------------
template <int ITERS>
__global__ __launch_bounds__(256) void k_stage1(const float* __restrict__ x,
                                                const float* __restrict__ w1,
                                                const float* __restrict__ w3,
                                                float* __restrict__ part,
                                                unsigned* __restrict__ wtab) {
  __shared__ __align__(16) char lds_raw[64 * 65 * 4];      // 16640 B
  unsigned short* As = (unsigned short*)lds_raw;           // 64 rows * 40 hw
  unsigned short* Bs = (unsigned short*)(lds_raw + 5120);  // 64 rows * 40 hw
  float* Cs = (float*)lds_raw;                             // 64 x 65 fp32

  const int tid = threadIdx.x;
  // w3 pack: layout dword d = [cio][kd][kh][chU][slot: A0 A1 B0 B1]
  if (blockIdx.x == 0) {
    int l = tid << 2;
#pragma unroll
    for (int j = 0; j < 4; ++j) {
      int d = l + j;
      int slot = d & 3, chU = (d >> 2) & 1, kh = (d >> 3) & 3,
          kd = (d >> 5) & 3, cio = d >> 7;
      int co = (chU << 1) + (slot & 1);
      int kwb = (slot >> 1) << 1;
      int base = ((co << 3) + cio) * 64 + (kd << 4) + (kh << 2) + kwb;
      wtab[d] = (unsigned)f2bf(w3[base]) | ((unsigned)f2bf(w3[base + 1]) << 16);
    }
  }

  const int ks = blockIdx.x >> 7;
  const int bt = (blockIdx.x >> 3) & 15;
  const int co = blockIdx.x & 7;
  const int w = tid >> 6, lane = tid & 63, lm = lane & 15, q = lane >> 4;
  const int rrow = tid & 63, kgr = tid >> 6;

  f32x4 acc[4];
#pragma unroll
  for (int i = 0; i < 4; ++i) acc[i] = (f32x4){0.f, 0.f, 0.f, 0.f};

  const float* gA = x + (bt << 16) + ((size_t)(ks * ITERS * 32) << 6);
  const float* gB = w1 + (co << 6) + (size_t)(ks * ITERS * 32) * 512;

  float va[2][8], vb[2][8];
#define S1_LOAD(buf, it)                            \
  {                                                 \
    const int kb = (it) * 32 + (kgr << 3);          \
    _Pragma("unroll") for (int j = 0; j < 8; ++j) { \
      va[buf][j] = gA[((kb + j) << 6) | rrow];      \
      vb[buf][j] = gB[(kb + j) * 512 + rrow];       \
    }                                               \
  }
  S1_LOAD(0, 0);
#pragma unroll
  for (int it = 0; it < ITERS; ++it) {
    const int cur = it & 1;
    if (it + 1 < ITERS) S1_LOAD(cur ^ 1, it + 1);
    uint4 pa, pb;
    pa.x = f2bf(va[cur][0]) | ((unsigned)f2bf(va[cur][1]) << 16);
    pa.y = f2bf(va[cur][2]) | ((unsigned)f2bf(va[cur][3]) << 16);
    pa.z = f2bf(va[cur][4]) | ((unsigned)f2bf(va[cur][5]) << 16);
    pa.w = f2bf(va[cur][6]) | ((unsigned)f2bf(va[cur][7]) << 16);
    pb.x = f2bf(vb[cur][0]) | ((unsigned)f2bf(vb[cur][1]) << 16);
    pb.y = f2bf(vb[cur][2]) | ((unsigned)f2bf(vb[cur][3]) << 16);
    pb.z = f2bf(vb[cur][4]) | ((unsigned)f2bf(vb[cur][5]) << 16);
    pb.w = f2bf(vb[cur][6]) | ((unsigned)f2bf(vb[cur][7]) << 16);
    *(uint4*)&As[rrow * 40 + (kgr << 3)] = pa;
    *(uint4*)&Bs[rrow * 40 + (kgr << 3)] = pb;
    __syncthreads();
    bf16x8 a = *(const bf16x8*)&As[((w << 4) + lm) * 40 + (q << 3)];
#pragma unroll
    for (int nf = 0; nf < 4; ++nf) {
      bf16x8 b = *(const bf16x8*)&Bs[((nf << 4) + lm) * 40 + (q << 3)];
      acc[nf] = __builtin_amdgcn_mfma_f32_16x16x32_bf16(a, b, acc[nf], 0, 0, 0);
    }
    __syncthreads();
  }
#undef S1_LOAD
  // ---- epilogue: C -> LDS transpose -> pos-linear scatter (stride 8 dw)
#pragma unroll
  for (int nf = 0; nf < 4; ++nf)
#pragma unroll
    for (int r = 0; r < 4; ++r) {
      int m = (w << 4) + (q << 2) + r;
      int n = (nf << 4) + lm;
      Cs[m * 65 + n] = acc[nf][r];
    }
  __syncthreads();
  float* dst = part + (((size_t)((ks << 4) + bt)) << 15) + co;
#pragma unroll
  for (int j = 0; j < 16; ++j) {
    int pos = (tid << 4) + j;
    int z = pos >> 8, y = (pos >> 4) & 15, xx = pos & 15;
    int m = ((z >> 2) << 4) + ((y >> 2) << 2) + (xx >> 2);
    int n = ((z & 3) << 4) + ((y & 3) << 2) + (xx & 3);
    dst[pos << 3] = Cs[m * 65 + n];
  }
}

// ---------------------------------------------------------------------------
// Fused stage 2+3 (R4 structure): 512 thr, 512 blocks, out tile z8 y16 x8,
// window 18x34 rows. w3 now comes from the global wtab via wave-uniform
// scalar loads (s_load_dwordx4); dot2 consumes the SGPR directly.
// ---------------------------------------------------------------------------
__global__ __launch_bounds__(512) void k_stage23(
    const float* __restrict__ part, const float* __restrict__ w2,
    const float* __restrict__ b2, const float* __restrict__ b3,
    const float* __restrict__ b1, const unsigned* __restrict__ wtab,
    float* __restrict__ out, int nsplit) {
  __shared__ __align__(16) unsigned win_d[18 * 34 * 12];  // 29376 B
  __shared__ __align__(16) unsigned h1p[6 * 240];         // bf16 pairs, 5760 B
  __shared__ __align__(16) unsigned w2p[8 * 320];         // bf16 pairs, 10240 B

  const int tid = threadIdx.x;
  const int bid = blockIdx.x;
  const int bt = bid >> 5;
  const int tile = bid & 31;
  const int tz = tile >> 3, ty = (tile >> 2) & 1, tx = tile & 3;
  const int Z0 = tz << 3, Y0 = ty << 4, X0 = tx << 3;
  const int Qz0 = (Z0 << 1) - 1, Qy0 = (Y0 << 1) - 1, Qx0 = (X0 << 1) - 1;
  const int Uz0 = (tz << 2) - 1, Uy0 = (ty << 3) - 1, Ux0 = (tx << 2) - 1;

  // ---- staging: h1 = tanh(sum_s part + b1), coalesced reads, bf16 LDS
  for (int l = tid; l < 2880; l += 512) {
    int ci = l & 7;
    int sp = l >> 3;
    int ux = sp % 6;
    int t1 = sp / 6;
    int uy = t1 % 10;
    int uz = t1 / 10;
    int gz = Uz0 + uz, gy = Uy0 + uy, gx = Ux0 + ux;
    float v = 0.f;
    if ((unsigned)gz < 16u && (unsigned)gy < 16u && (unsigned)gx < 16u) {
      const float* p =
          part + (((size_t)bt << 12) + (gz << 8) + (gy << 4) + gx) * 8 + ci;
      float s = b1[ci];
      for (int sg = 0; sg < nsplit; ++sg) s += p[(size_t)sg << 19];
      v = fast_tanh(s);
    }
    ((unsigned short*)h1p)[uz * 480 + uy * 48 + (ux << 3) + ci] = f2bf(v);
  }
  // w2 packed: dword = [cio][kz*4+ky (stride 20dw)][kx*4 + jpair]
  for (int l = tid; l < 2048; l += 512) {
    int j = l & 3, kx = (l >> 2) & 3, kzy = (l >> 4) & 15, cio = l >> 8;
    int kpos = (kzy << 2) + kx;
    float w0 = w2[(((j << 1) << 3) + cio) * 64 + kpos];
    float w1v = w2[((((j << 1) + 1) << 3) + cio) * 64 + kpos];
    w2p[cio * 320 + kzy * 20 + (kx << 2) + j] =
        (unsigned)f2bf(w0) | ((unsigned)f2bf(w1v) << 16);
  }

  float acc[2][4];  // [cc][i]
#pragma unroll
  for (int a = 0; a < 2; ++a)
#pragma unroll
    for (int i = 0; i < 4; ++i) acc[a][i] = 0.f;

  const int xh = tid & 1, yq = (tid >> 1) & 15, zq = (tid >> 5) & 7;
  const int chS = __builtin_amdgcn_readfirstlane(tid >> 8);  // wave-uniform

  for (int cio = 0; cio < 8; ++cio) {
    __syncthreads();  // prev conv done reading win (covers staging too)
    const float b2c = b2[cio];
    // ---- fill window: 1224 units = (wz 18) x (wy 34) x (half 2)
    for (int u = tid; u < 1224; u += 512) {
      int wz = u / 68;
      int rem = u - wz * 68;
      int wy = rem >> 1;
      int half = rem & 1;
      unsigned* wrow = win_d + (wz * 34 + wy) * 12;
      int qz = Qz0 + wz, qy = Qy0 + wy;
      if ((unsigned)qz < 64u && (unsigned)qy < 64u) {
        int kz = qz & 3, ky = qy & 3;
        int uzp = (qz >> 2) - Uz0, uyp = (qy >> 2) - Uy0;
        const unsigned* w2b = w2p + cio * 320 + ((kz << 2) + ky) * 20;
        uint4 wv[4];
#pragma unroll
        for (int kx = 0; kx < 4; ++kx) wv[kx] = *(const uint4*)(w2b + (kx << 2));
        const unsigned* h1b = h1p + uzp * 240 + uyp * 24;
#define DOT8(hc, kx)                                               \
  dot2bf((hc).w, wv[kx].w,                                         \
         dot2bf((hc).z, wv[kx].z,                                  \
                dot2bf((hc).y, wv[kx].y, dot2bf((hc).x, wv[kx].x, b2c))))
        if (half == 0) {  // wx 0..7: cell0 kx3(guard), cell1 kx0-3, cell2 kx0-2
          uint4 h0 = *(const uint4*)(h1b);
          uint4 h1c = *(const uint4*)(h1b + 4);
          uint4 h2c = *(const uint4*)(h1b + 8);
          float vals[8];
          vals[0] = (Qx0 >= 0) ? fast_tanh(DOT8(h0, 3)) : 0.f;
#pragma unroll
          for (int kx = 0; kx < 4; ++kx) vals[1 + kx] = fast_tanh(DOT8(h1c, kx));
#pragma unroll
          for (int kx = 0; kx < 3; ++kx) vals[5 + kx] = fast_tanh(DOT8(h2c, kx));
          uint4 s0;
          s0.x = f2bf(vals[0]) | ((unsigned)f2bf(vals[1]) << 16);
          s0.y = f2bf(vals[2]) | ((unsigned)f2bf(vals[3]) << 16);
          s0.z = f2bf(vals[4]) | ((unsigned)f2bf(vals[5]) << 16);
          s0.w = f2bf(vals[6]) | ((unsigned)f2bf(vals[7]) << 16);
          *(uint4*)wrow = s0;
        } else {  // wx 8..17: cell2 kx3, cell3 kx0-3, cell4 kx0-3, cell5 kx0(guard)
          uint4 h2c = *(const uint4*)(h1b + 8);
          uint4 h3 = *(const uint4*)(h1b + 12);
          uint4 h4 = *(const uint4*)(h1b + 16);
          uint4 h5 = *(const uint4*)(h1b + 20);
          float vals[10];
          vals[0] = fast_tanh(DOT8(h2c, 3));
#pragma unroll
          for (int kx = 0; kx < 4; ++kx) vals[1 + kx] = fast_tanh(DOT8(h3, kx));
#pragma unroll
          for (int kx = 0; kx < 4; ++kx) vals[5 + kx] = fast_tanh(DOT8(h4, kx));
          vals[9] = (Qx0 + 17 < 64) ? fast_tanh(DOT8(h5, 0)) : 0.f;
          uint4 s1;
          s1.x = f2bf(vals[0]) | ((unsigned)f2bf(vals[1]) << 16);
          s1.y = f2bf(vals[2]) | ((unsigned)f2bf(vals[3]) << 16);
          s1.z = f2bf(vals[4]) | ((unsigned)f2bf(vals[5]) << 16);
          s1.w = f2bf(vals[6]) | ((unsigned)f2bf(vals[7]) << 16);
          *(uint4*)(wrow + 4) = s1;
          wrow[8] = f2bf(vals[8]) | ((unsigned)f2bf(vals[9]) << 16);
        }
#undef DOT8
      } else {
        uint4 zz;
        zz.x = zz.y = zz.z = zz.w = 0u;
        if (half == 0) {
          *(uint4*)wrow = zz;
        } else {
          *(uint4*)(wrow + 4) = zz;
          wrow[8] = 0u;
        }
      }
    }
    __syncthreads();
    // ---- conv3 accumulation for this cio: w3 via scalar loads, win via LDS
#pragma unroll
    for (int kd = 0; kd < 4; ++kd) {
      int wz = (zq << 1) + kd;
#pragma unroll
      for (int kh = 0; kh < 4; ++kh) {
        int wy = (yq << 1) + kh;
        const unsigned* rowp = win_d + (wz * 34 + wy) * 12 + (xh << 2);
        uint4 rv = *(const uint4*)rowp;
        unsigned r4 = rowp[4];
        unsigned r[5] = {rv.x, rv.y, rv.z, rv.w, r4};
        const uint4 wv =
            *(const uint4*)&wtab[((((cio << 4) + (kd << 2) + kh) << 1) + chS)
                                 << 2];
        unsigned wA[2] = {wv.x, wv.y};
        unsigned wB[2] = {wv.z, wv.w};
#pragma unroll
        for (int cc = 0; cc < 2; ++cc) {
#pragma unroll
          for (int i = 0; i < 4; ++i) {
            float a0 = dot2bf(r[i], wA[cc], acc[cc][i]);
            acc[cc][i] = dot2bf(r[i + 1], wB[cc], a0);
          }
        }
      }
    }
  }
  // ---- epilogue: + b3, store to (B, C, 32,32,32, T) with t innermost
  const int ch = tid >> 8;
  const int b = bt >> 3, t8 = bt & 7;
  const int z = Z0 + zq;
  const int y = Y0 + yq;
#pragma unroll
  for (int cc = 0; cc < 2; ++cc) {
    int c4 = (ch << 1) + cc;
    float bias = b3[c4];
#pragma unroll
    for (int i = 0; i < 4; ++i) {
      int xx = X0 + (xh << 2) + i;
      out[(((((b << 2) + c4) * 32 + z) * 32 + y) * 32 + xx) << 3 | t8] =
          acc[cc][i] + bias;
    }
  }
}

extern "C" void kernel_launch(void* const* d_in, const int* in_sizes, int n_in,
                              void* d_out, int out_size, void* d_ws,
                              size_t ws_size, hipStream_t stream) {
  (void)in_sizes; (void)n_in; (void)out_size;
  const float* x = (const float*)d_in[0];
  const float* w1 = (const float*)d_in[1];
  const float* b1 = (const float*)d_in[2];
  const float* w2 = (const float*)d_in[3];
  const float* b2 = (const float*)d_in[4];
  const float* w3 = (const float*)d_in[5];
  const float* b3 = (const float*)d_in[6];
  float* out = (float*)d_out;
  float* part = (float*)d_ws;

  const size_t plane = (size_t)16 * 8 * 4096;  // floats per split (2 MB)
  int nsplit = (ws_size >= 2 * plane * 4 + 4096) ? 2 : 1;
  unsigned* wtab = (unsigned*)(part + (size_t)nsplit * plane);

  if (nsplit == 2)
    k_stage1<16><<<dim3(256), dim3(256), 0, stream>>>(x, w1, w3, part, wtab);
  else
    k_stage1<32><<<dim3(128), dim3(256), 0, stream>>>(x, w1, w3, part, wtab);
  k_stage23<<<dim3(512), dim3(512), 0, stream>>>(part, w2, b2, b3, b1, wtab,
                                                 out, nsplit);
}

// Round 7
// 151.130 us; speedup vs baseline: 1.0871x; 1.0384x over previous
//
#include <hip/hip_runtime.h>
#include <cstdint>

typedef short bf16x8 __attribute__((ext_vector_type(8)));
typedef float f32x4 __attribute__((ext_vector_type(4)));
typedef _Float16 half2_t __attribute__((ext_vector_type(2)));

__device__ __forceinline__ unsigned short f2bf(float f) {
  unsigned u = __builtin_bit_cast(unsigned, f);
  u += 0x7fffu + ((u >> 16) & 1u);  // RNE
  return (unsigned short)(u >> 16);
}
__device__ __forceinline__ unsigned pkh2(float a, float b) {
  return __builtin_bit_cast(unsigned, __builtin_amdgcn_cvt_pkrtz(a, b));
}
__device__ __forceinline__ float fast_tanh(float x) {
  float e = __builtin_amdgcn_exp2f(x * 2.885390081777927f);
  return 1.0f - 2.0f * __builtin_amdgcn_rcpf(e + 1.0f);
}

// Packed fp16 pair dot with f32 accumulate: d = a.lo*b.lo + a.hi*b.hi + c
#if __has_builtin(__builtin_amdgcn_fdot2)
__device__ __forceinline__ float dot2h(unsigned a, unsigned b, float c) {
  return __builtin_amdgcn_fdot2(__builtin_bit_cast(half2_t, a),
                                __builtin_bit_cast(half2_t, b), c, false);
}
#else
__device__ __forceinline__ float dot2h(unsigned a, unsigned b, float c) {
  half2_t av = __builtin_bit_cast(half2_t, a);
  half2_t bv = __builtin_bit_cast(half2_t, b);
  c = fmaf((float)av.x, (float)bv.x, c);
  c = fmaf((float)av.y, (float)bv.y, c);
  return c;
}
#endif

// ---------------------------------------------------------------------------
// Stage 1: per-(ks,bt,co) partial GEMM, M=64(ipos) N=64(kpos) K=1024/nsplit.
// bf16 MFMA; epilogue -> channel-last part[ks][bt][pos][ci] (L2-absorbed).
// Block 0 packs w3 into wtab (fp16 pairs) for stage23's scalar loads.
// ---------------------------------------------------------------------------
template <int ITERS>
__global__ __launch_bounds__(256) void k_stage1(const float* __restrict__ x,
                                                const float* __restrict__ w1,
                                                const float* __restrict__ w3,
                                                float* __restrict__ part,
                                                unsigned* __restrict__ wtab) {
  __shared__ __align__(16) char lds_raw[64 * 65 * 4];      // 16640 B
  unsigned short* As = (unsigned short*)lds_raw;           // 64 rows * 40 hw
  unsigned short* Bs = (unsigned short*)(lds_raw + 5120);  // 64 rows * 40 hw
  float* Cs = (float*)lds_raw;                             // 64 x 65 fp32

  const int tid = threadIdx.x;
  // w3 pack: dword d = [cio][kd][kh][chU][slot: A0 A1 B0 B1], fp16 pairs
  if (blockIdx.x == 0) {
    int l = tid << 2;
#pragma unroll
    for (int j = 0; j < 4; ++j) {
      int d = l + j;
      int slot = d & 3, chU = (d >> 2) & 1, kh = (d >> 3) & 3,
          kd = (d >> 5) & 3, cio = d >> 7;
      int co = (chU << 1) + (slot & 1);
      int kwb = (slot >> 1) << 1;
      int base = ((co << 3) + cio) * 64 + (kd << 4) + (kh << 2) + kwb;
      wtab[d] = pkh2(w3[base], w3[base + 1]);
    }
  }

  const int ks = blockIdx.x >> 7;
  const int bt = (blockIdx.x >> 3) & 15;
  const int co = blockIdx.x & 7;
  const int w = tid >> 6, lane = tid & 63, lm = lane & 15, q = lane >> 4;
  const int rrow = tid & 63, kgr = tid >> 6;

  f32x4 acc[4];
#pragma unroll
  for (int i = 0; i < 4; ++i) acc[i] = (f32x4){0.f, 0.f, 0.f, 0.f};

  const float* gA = x + (bt << 16) + ((size_t)(ks * ITERS * 32) << 6);
  const float* gB = w1 + (co << 6) + (size_t)(ks * ITERS * 32) * 512;

  float va[2][8], vb[2][8];
#define S1_LOAD(buf, it)                            \
  {                                                 \
    const int kb = (it) * 32 + (kgr << 3);          \
    _Pragma("unroll") for (int j = 0; j < 8; ++j) { \
      va[buf][j] = gA[((kb + j) << 6) | rrow];      \
      vb[buf][j] = gB[(kb + j) * 512 + rrow];       \
    }                                               \
  }
  S1_LOAD(0, 0);
#pragma unroll
  for (int it = 0; it < ITERS; ++it) {
    const int cur = it & 1;
    if (it + 1 < ITERS) S1_LOAD(cur ^ 1, it + 1);
    uint4 pa, pb;
    pa.x = f2bf(va[cur][0]) | ((unsigned)f2bf(va[cur][1]) << 16);
    pa.y = f2bf(va[cur][2]) | ((unsigned)f2bf(va[cur][3]) << 16);
    pa.z = f2bf(va[cur][4]) | ((unsigned)f2bf(va[cur][5]) << 16);
    pa.w = f2bf(va[cur][6]) | ((unsigned)f2bf(va[cur][7]) << 16);
    pb.x = f2bf(vb[cur][0]) | ((unsigned)f2bf(vb[cur][1]) << 16);
    pb.y = f2bf(vb[cur][2]) | ((unsigned)f2bf(vb[cur][3]) << 16);
    pb.z = f2bf(vb[cur][4]) | ((unsigned)f2bf(vb[cur][5]) << 16);
    pb.w = f2bf(vb[cur][6]) | ((unsigned)f2bf(vb[cur][7]) << 16);
    *(uint4*)&As[rrow * 40 + (kgr << 3)] = pa;
    *(uint4*)&Bs[rrow * 40 + (kgr << 3)] = pb;
    __syncthreads();
    bf16x8 a = *(const bf16x8*)&As[((w << 4) + lm) * 40 + (q << 3)];
#pragma unroll
    for (int nf = 0; nf < 4; ++nf) {
      bf16x8 b = *(const bf16x8*)&Bs[((nf << 4) + lm) * 40 + (q << 3)];
      acc[nf] = __builtin_amdgcn_mfma_f32_16x16x32_bf16(a, b, acc[nf], 0, 0, 0);
    }
    __syncthreads();
  }
#undef S1_LOAD
  // ---- epilogue: C -> LDS transpose -> pos-linear scatter (stride 8 dw)
#pragma unroll
  for (int nf = 0; nf < 4; ++nf)
#pragma unroll
    for (int r = 0; r < 4; ++r) {
      int m = (w << 4) + (q << 2) + r;
      int n = (nf << 4) + lm;
      Cs[m * 65 + n] = acc[nf][r];
    }
  __syncthreads();
  float* dst = part + (((size_t)((ks << 4) + bt)) << 15) + co;
#pragma unroll
  for (int j = 0; j < 16; ++j) {
    int pos = (tid << 4) + j;
    int z = pos >> 8, y = (pos >> 4) & 15, xx = pos & 15;
    int m = ((z >> 2) << 4) + ((y >> 2) << 2) + (xx >> 2);
    int n = ((z & 3) << 4) + ((y & 3) << 2) + (xx & 3);
    dst[pos << 3] = Cs[m * 65 + n];
  }
}

// ---------------------------------------------------------------------------
// Fused stage 2+3: 512 thr, 512 blocks, out tile z8 y16 x8, window 18x34.
// All packed pairs are FP16 (v_dot2_f32_f16 via __builtin_amdgcn_fdot2,
// packing via v_cvt_pkrtz). Window double-buffered: ONE barrier per cio,
// conv(cio) overlaps fill(cio+1). w3 via wave-uniform scalar loads.
// ---------------------------------------------------------------------------
__global__ __launch_bounds__(512) void k_stage23(
    const float* __restrict__ part, const float* __restrict__ w2,
    const float* __restrict__ b2, const float* __restrict__ b3,
    const float* __restrict__ b1, const unsigned* __restrict__ wtab,
    float* __restrict__ out, int nsplit) {
  __shared__ __align__(16) unsigned win_d[2][18 * 34 * 12];  // 58752 B
  __shared__ __align__(16) unsigned h1p[6 * 240];            // fp16 pairs
  __shared__ __align__(16) unsigned w2p[8 * 320];            // fp16 pairs

  const int tid = threadIdx.x;
  const int bid = blockIdx.x;
  const int bt = bid >> 5;
  const int tile = bid & 31;
  const int tz = tile >> 3, ty = (tile >> 2) & 1, tx = tile & 3;
  const int Z0 = tz << 3, Y0 = ty << 4, X0 = tx << 3;
  const int Qz0 = (Z0 << 1) - 1, Qy0 = (Y0 << 1) - 1, Qx0 = (X0 << 1) - 1;
  const int Uz0 = (tz << 2) - 1, Uy0 = (ty << 3) - 1, Ux0 = (tx << 2) - 1;

  // ---- staging: h1 = tanh(sum_s part + b1) -> fp16 LDS (coalesced reads)
  for (int l = tid; l < 2880; l += 512) {
    int ci = l & 7;
    int sp = l >> 3;
    int ux = sp % 6;
    int t1 = sp / 6;
    int uy = t1 % 10;
    int uz = t1 / 10;
    int gz = Uz0 + uz, gy = Uy0 + uy, gx = Ux0 + ux;
    float v = 0.f;
    if ((unsigned)gz < 16u && (unsigned)gy < 16u && (unsigned)gx < 16u) {
      const float* p =
          part + (((size_t)bt << 12) + (gz << 8) + (gy << 4) + gx) * 8 + ci;
      float s = b1[ci];
      for (int sg = 0; sg < nsplit; ++sg) s += p[(size_t)sg << 19];
      v = fast_tanh(s);
    }
    ((_Float16*)h1p)[uz * 480 + uy * 48 + (ux << 3) + ci] = (_Float16)v;
  }
  // w2 packed: dword = [cio][kz*4+ky (stride 20dw)][kx*4 + jpair]
  for (int l = tid; l < 2048; l += 512) {
    int j = l & 3, kx = (l >> 2) & 3, kzy = (l >> 4) & 15, cio = l >> 8;
    int kpos = (kzy << 2) + kx;
    float w0 = w2[(((j << 1) << 3) + cio) * 64 + kpos];
    float w1v = w2[((((j << 1) + 1) << 3) + cio) * 64 + kpos];
    w2p[cio * 320 + kzy * 20 + (kx << 2) + j] = pkh2(w0, w1v);
  }
  // ---- prepass: zero OOB rows of BOTH window buffers (skipped in-loop)
  for (int u = tid; u < 1224; u += 512) {
    int wz = u / 68;
    int rem = u - wz * 68;
    int wy = rem >> 1;
    int half = rem & 1;
    int qz = Qz0 + wz, qy = Qy0 + wy;
    if ((unsigned)qz < 64u && (unsigned)qy < 64u) continue;
    uint4 zz;
    zz.x = zz.y = zz.z = zz.w = 0u;
#pragma unroll
    for (int bsel = 0; bsel < 2; ++bsel) {
      unsigned* wrow = win_d[bsel] + (wz * 34 + wy) * 12;
      if (half == 0) {
        *(uint4*)wrow = zz;
      } else {
        *(uint4*)(wrow + 4) = zz;
        wrow[8] = 0u;
      }
    }
  }
  __syncthreads();  // staging + prepass visible

  float acc[2][4];  // [cc][i]
#pragma unroll
  for (int a = 0; a < 2; ++a)
#pragma unroll
    for (int i = 0; i < 4; ++i) acc[a][i] = 0.f;

  const int xh = tid & 1, yq = (tid >> 1) & 15, zq = (tid >> 5) & 7;
  const int chS = __builtin_amdgcn_readfirstlane(tid >> 8);  // wave-uniform

  for (int cio = 0; cio < 8; ++cio) {
    unsigned* wbuf = win_d[cio & 1];
    const float b2c = b2[cio];
    // ---- fill window: 1224 units = (wz 18) x (wy 34) x (half 2)
    for (int u = tid; u < 1224; u += 512) {
      int wz = u / 68;
      int rem = u - wz * 68;
      int wy = rem >> 1;
      int half = rem & 1;
      int qz = Qz0 + wz, qy = Qy0 + wy;
      if (!((unsigned)qz < 64u && (unsigned)qy < 64u)) continue;
      unsigned* wrow = wbuf + (wz * 34 + wy) * 12;
      int kz = qz & 3, ky = qy & 3;
      int uzp = (qz >> 2) - Uz0, uyp = (qy >> 2) - Uy0;
      const unsigned* w2b = w2p + cio * 320 + ((kz << 2) + ky) * 20;
      uint4 wv[4];
#pragma unroll
      for (int kx = 0; kx < 4; ++kx) wv[kx] = *(const uint4*)(w2b + (kx << 2));
      const unsigned* h1b = h1p + uzp * 240 + uyp * 24;
#define DOT8(hc, kx)                                            \
  dot2h((hc).w, wv[kx].w,                                       \
        dot2h((hc).z, wv[kx].z,                                 \
              dot2h((hc).y, wv[kx].y, dot2h((hc).x, wv[kx].x, b2c))))
      if (half == 0) {  // wx 0..7: cell0 kx3(guard), cell1 kx0-3, cell2 kx0-2
        uint4 h0 = *(const uint4*)(h1b);
        uint4 h1c = *(const uint4*)(h1b + 4);
        uint4 h2c = *(const uint4*)(h1b + 8);
        float vals[8];
        vals[0] = (Qx0 >= 0) ? fast_tanh(DOT8(h0, 3)) : 0.f;
#pragma unroll
        for (int kx = 0; kx < 4; ++kx) vals[1 + kx] = fast_tanh(DOT8(h1c, kx));
#pragma unroll
        for (int kx = 0; kx < 3; ++kx) vals[5 + kx] = fast_tanh(DOT8(h2c, kx));
        uint4 s0;
        s0.x = pkh2(vals[0], vals[1]);
        s0.y = pkh2(vals[2], vals[3]);
        s0.z = pkh2(vals[4], vals[5]);
        s0.w = pkh2(vals[6], vals[7]);
        *(uint4*)wrow = s0;
      } else {  // wx 8..17: cell2 kx3, cell3 kx0-3, cell4 kx0-3, cell5 kx0(g)
        uint4 h2c = *(const uint4*)(h1b + 8);
        uint4 h3 = *(const uint4*)(h1b + 12);
        uint4 h4 = *(const uint4*)(h1b + 16);
        uint4 h5 = *(const uint4*)(h1b + 20);
        float vals[10];
        vals[0] = fast_tanh(DOT8(h2c, 3));
#pragma unroll
        for (int kx = 0; kx < 4; ++kx) vals[1 + kx] = fast_tanh(DOT8(h3, kx));
#pragma unroll
        for (int kx = 0; kx < 4; ++kx) vals[5 + kx] = fast_tanh(DOT8(h4, kx));
        vals[9] = (Qx0 + 17 < 64) ? fast_tanh(DOT8(h5, 0)) : 0.f;
        uint4 s1;
        s1.x = pkh2(vals[0], vals[1]);
        s1.y = pkh2(vals[2], vals[3]);
        s1.z = pkh2(vals[4], vals[5]);
        s1.w = pkh2(vals[6], vals[7]);
        *(uint4*)(wrow + 4) = s1;
        wrow[8] = pkh2(vals[8], vals[9]);
      }
#undef DOT8
    }
    __syncthreads();  // fill(cio) complete; conv(cio) overlaps fill(cio+1)
    // ---- conv3 accumulation: w3 scalar loads, win LDS rows
#pragma unroll
    for (int kd = 0; kd < 4; ++kd) {
      int wz = (zq << 1) + kd;
#pragma unroll
      for (int kh = 0; kh < 4; ++kh) {
        int wy = (yq << 1) + kh;
        const unsigned* rowp = wbuf + (wz * 34 + wy) * 12 + (xh << 2);
        uint4 rv = *(const uint4*)rowp;
        unsigned r4 = rowp[4];
        unsigned r[5] = {rv.x, rv.y, rv.z, rv.w, r4};
        const uint4 wv =
            *(const uint4*)&wtab[((((cio << 4) + (kd << 2) + kh) << 1) + chS)
                                 << 2];
        unsigned wA[2] = {wv.x, wv.y};
        unsigned wB[2] = {wv.z, wv.w};
#pragma unroll
        for (int cc = 0; cc < 2; ++cc) {
#pragma unroll
          for (int i = 0; i < 4; ++i) {
            float a0 = dot2h(r[i], wA[cc], acc[cc][i]);
            acc[cc][i] = dot2h(r[i + 1], wB[cc], a0);
          }
        }
      }
    }
  }
  // ---- epilogue: + b3, store to (B, C, 32,32,32, T) with t innermost
  const int ch = tid >> 8;
  const int b = bt >> 3, t8 = bt & 7;
  const int z = Z0 + zq;
  const int y = Y0 + yq;
#pragma unroll
  for (int cc = 0; cc < 2; ++cc) {
    int c4 = (ch << 1) + cc;
    float bias = b3[c4];
#pragma unroll
    for (int i = 0; i < 4; ++i) {
      int xx = X0 + (xh << 2) + i;
      out[(((((b << 2) + c4) * 32 + z) * 32 + y) * 32 + xx) << 3 | t8] =
          acc[cc][i] + bias;
    }
  }
}

extern "C" void kernel_launch(void* const* d_in, const int* in_sizes, int n_in,
                              void* d_out, int out_size, void* d_ws,
                              size_t ws_size, hipStream_t stream) {
  (void)in_sizes; (void)n_in; (void)out_size;
  const float* x = (const float*)d_in[0];
  const float* w1 = (const float*)d_in[1];
  const float* b1 = (const float*)d_in[2];
  const float* w2 = (const float*)d_in[3];
  const float* b2 = (const float*)d_in[4];
  const float* w3 = (const float*)d_in[5];
  const float* b3 = (const float*)d_in[6];
  float* out = (float*)d_out;
  float* part = (float*)d_ws;

  const size_t plane = (size_t)16 * 8 * 4096;  // floats per split (2 MB)
  int nsplit = (ws_size >= 2 * plane * 4 + 4096) ? 2 : 1;
  unsigned* wtab = (unsigned*)(part + (size_t)nsplit * plane);

  if (nsplit == 2)
    k_stage1<16><<<dim3(256), dim3(256), 0, stream>>>(x, w1, w3, part, wtab);
  else
    k_stage1<32><<<dim3(128), dim3(256), 0, stream>>>(x, w1, w3, part, wtab);
  k_stage23<<<dim3(512), dim3(512), 0, stream>>>(part, w2, b2, b3, b1, wtab,
                                                 out, nsplit);
}